// Round 9
// baseline (463.723 us; speedup 1.0000x reference)
//
#include <hip/hip_runtime.h>

#define N_NODES 100000
#define N_EDGES 1600000
#define EMB 128
#define BM 16
#define NSLAB 64
#define BN_EPS 1e-5f

#define SCAN_BLK 512
#define NB_SCAN ((N_NODES + SCAN_BLK - 1) / SCAN_BLK)   // 196
#define NPAD (NB_SCAN * SCAN_BLK)                       // 100352

typedef short short8 __attribute__((ext_vector_type(8)));
typedef float floatx4 __attribute__((ext_vector_type(4)));

__device__ __forceinline__ ushort f2bf(float x) {
    unsigned u = __float_as_uint(x);
    u += 0x7fffu + ((u >> 16) & 1u);   // RNE
    return (ushort)(u >> 16);
}
__device__ __forceinline__ float lo2f(unsigned p) {    // low bf16 of packed u32
    return __uint_as_float(p << 16);
}
__device__ __forceinline__ float hi2f(unsigned p) {    // high bf16 of packed u32
    return __uint_as_float(p & 0xffff0000u);
}

// =================== setup: nf->bf16 + dst histogram + weight frags =========
__global__ __launch_bounds__(256) void setup_kernel(
    const float* __restrict__ nf, ushort* __restrict__ nfbf,
    const int* __restrict__ dst, int* __restrict__ counts,
    const float* __restrict__ W1, const float* __restrict__ W2,
    ushort* __restrict__ w1f, ushort* __restrict__ w2f)
{
    int gtid = blockIdx.x * 256 + threadIdx.x;
    long gstride = (long)gridDim.x * 256;

    if (gtid < 65536) {
        int idx = gtid;
        int i = idx & 7;
        int lane = (idx >> 3) & 63;
        int kloc = ((lane >> 4) << 3) + i;
        int nloc = lane & 15;
        if (idx < 32768) {
            int ks = (idx >> 9) & 3, nt = idx >> 11;
            w1f[idx] = f2bf(W1[(ks * 32 + kloc) * 256 + nt * 16 + nloc]);
        } else {
            int j = idx - 32768;
            int ks = (j >> 9) & 7, nt = j >> 12;
            w2f[j] = f2bf(W2[(ks * 32 + kloc) * 128 + nt * 16 + nloc]);
        }
    }

    long total = (long)N_NODES * EMB / 4;
    for (long p = gtid; p < total; p += gstride) {
        float4 v = ((const float4*)nf)[p];
        ushort4 o;
        o.x = f2bf(v.x); o.y = f2bf(v.y); o.z = f2bf(v.z); o.w = f2bf(v.w);
        ((ushort4*)nfbf)[p] = o;
    }

    for (long e = gtid; e < N_EDGES; e += gstride)
        atomicAdd(&counts[dst[e]], 1);
}

// =================== scan machinery (2 kernels) ===================
__global__ __launch_bounds__(SCAN_BLK) void scan_blocksum_kernel(
    const int* __restrict__ counts, int* __restrict__ blockSums)
{
    __shared__ int red[SCAN_BLK];
    int t = threadIdx.x;
    int i = blockIdx.x * SCAN_BLK + t;
    red[t] = (i < N_NODES) ? counts[i] : 0;
    __syncthreads();
    for (int s = SCAN_BLK / 2; s > 0; s >>= 1) {
        if (t < s) red[t] += red[t + s];
        __syncthreads();
    }
    if (t == 0) blockSums[blockIdx.x] = red[0];
}

// scans blockSums locally (196 entries) AND the per-element counts
__global__ __launch_bounds__(SCAN_BLK) void scan_final_kernel(
    const int* __restrict__ counts, const int* __restrict__ blockSums,
    int* __restrict__ offsets, int* __restrict__ cursor)
{
    __shared__ int s[SCAN_BLK];
    __shared__ int bs[256];
    int t = threadIdx.x;
    if (t < 256) bs[t] = (t < NB_SCAN) ? blockSums[t] : 0;
    __syncthreads();
    for (int off = 1; off < 256; off <<= 1) {
        int v = (t < 256 && t >= off) ? bs[t - off] : 0;
        __syncthreads();
        if (t < 256) bs[t] += v;
        __syncthreads();
    }
    int blockBase = (blockIdx.x == 0) ? 0 : bs[blockIdx.x - 1];

    int i = blockIdx.x * SCAN_BLK + t;
    int orig = (i < N_NODES) ? counts[i] : 0;
    s[t] = orig;
    __syncthreads();
    for (int off = 1; off < SCAN_BLK; off <<= 1) {
        int v = (t >= off) ? s[t - off] : 0;
        __syncthreads();
        s[t] += v;
        __syncthreads();
    }
    int excl = s[t] - orig + blockBase;
    if (i < N_NODES) { offsets[i] = excl; cursor[i] = excl; }
    if (i == N_NODES) offsets[N_NODES] = N_EDGES;
}

// =================== scatter: 24B records {src, 9xbf16} sorted by dst =======
__global__ __launch_bounds__(256) void scatter24_kernel(
    const int* __restrict__ src, const int* __restrict__ dst,
    const float* __restrict__ ef0, const float* __restrict__ ef1,
    int* __restrict__ cursor, int* __restrict__ rec24)
{
    int e = blockIdx.x * 256 + threadIdx.x;
    if (e >= N_EDGES) return;
    int t = dst[e];
    int pos = atomicAdd(&cursor[t], 1);

    const float2* p0 = (const float2*)(ef0 + (long)e * 6);
    float2 q0 = p0[0], q1 = p0[1], q2 = p0[2];
    const float* p1 = ef1 + (long)e * 3;
    float g0 = p1[0], g1 = p1[1], g2 = p1[2];

    unsigned u0 = (unsigned)f2bf(q0.x) | ((unsigned)f2bf(q0.y) << 16);
    unsigned u1 = (unsigned)f2bf(q1.x) | ((unsigned)f2bf(q1.y) << 16);
    unsigned u2 = (unsigned)f2bf(q2.x) | ((unsigned)f2bf(q2.y) << 16);
    unsigned u3 = (unsigned)f2bf(g0)   | ((unsigned)f2bf(g1) << 16);
    unsigned u4 = (unsigned)f2bf(g2);

    int2* out = (int2*)(rec24 + (long)pos * 6);
    out[0] = make_int2(src[e], (int)u0);
    out[1] = make_int2((int)u1, (int)u2);
    out[2] = make_int2((int)u3, (int)u4);
}

// =================== FUSED gather + MFMA MLP + BN stats =====================
// Block = 32 nodes, 4 waves. Phase 1: wave wv gathers nodes wv*8..wv*8+7
// (quarter-wave row loads, 4 rows in flight) -> bf16 rows in swizzled LDS.
// Phase 2: MFMA MLP (GEMM1 relu GEMM2) from LDS -> h (d_out) + BN stats.
__global__ __launch_bounds__(256) void gather_mlp_kernel(
    const ushort* __restrict__ nfbf, const int* __restrict__ rec24,
    const int* __restrict__ offsets,
    const float* __restrict__ We0, const float* __restrict__ be0,
    const float* __restrict__ We1, const float* __restrict__ be1,
    const ushort* __restrict__ w1f, const ushort* __restrict__ w2f,
    const float* __restrict__ b1, const float* __restrict__ b2,
    float* __restrict__ h, float* __restrict__ stats)
{
    __shared__ __align__(16) char aggS[32 * 256];   // 32 rows x 128 bf16, swizzled
    __shared__ __align__(16) char h1S[32 * 512];    // 32 rows x 256 bf16, swizzled

    int tid = threadIdx.x;
    int lane = tid & 63;
    int wv = tid >> 6;
    int q = lane >> 4, lp = lane & 15;
    long nbase = (long)blockIdx.x * 32;
    const int4* nf16 = (const int4*)nfbf;   // row = 16 int4

    // ---------------- phase 1: gather 8 nodes per wave ----------------
#pragma unroll 1
    for (int t = 0; t < 8; ++t) {
        int row = wv * 8 + t;
        int n = (int)nbase + row;
        int beg = offsets[n], end = offsets[n + 1];
        float4 accA = make_float4(0.f, 0.f, 0.f, 0.f);
        float4 accB = make_float4(0.f, 0.f, 0.f, 0.f);
        float fs0 = 0.f, fs1 = 0.f, fs2 = 0.f, fs3 = 0.f, fs4 = 0.f,
              fs5 = 0.f, fs6 = 0.f, fs7 = 0.f, fs8 = 0.f;

        int base = beg;
        for (; base + 64 <= end; base += 64) {
            const int2* rp = (const int2*)(rec24 + (long)(base + lane) * 6);
            int2 ra = rp[0], rb = rp[1], rc = rp[2];
            int sid = ra.x;
            fs0 += lo2f((unsigned)ra.y); fs1 += hi2f((unsigned)ra.y);
            fs2 += lo2f((unsigned)rb.x); fs3 += hi2f((unsigned)rb.x);
            fs4 += lo2f((unsigned)rb.y); fs5 += hi2f((unsigned)rb.y);
            fs6 += lo2f((unsigned)rc.x); fs7 += hi2f((unsigned)rc.x);
            fs8 += lo2f((unsigned)rc.y);
#pragma unroll 4
            for (int j = 0; j < 16; ++j) {
                int s = __shfl(sid, 4 * j + q);
                int4 nv = nf16[(long)s * 16 + lp];
                accA.x += lo2f((unsigned)nv.x); accA.y += hi2f((unsigned)nv.x);
                accA.z += lo2f((unsigned)nv.y); accA.w += hi2f((unsigned)nv.y);
                accB.x += lo2f((unsigned)nv.z); accB.y += hi2f((unsigned)nv.z);
                accB.z += lo2f((unsigned)nv.w); accB.w += hi2f((unsigned)nv.w);
            }
        }
        if (base < end) {
            int m = end - base;
            int sid = 0;
            if (lane < m) {
                const int2* rp = (const int2*)(rec24 + (long)(base + lane) * 6);
                int2 ra = rp[0], rb = rp[1], rc = rp[2];
                sid = ra.x;
                fs0 += lo2f((unsigned)ra.y); fs1 += hi2f((unsigned)ra.y);
                fs2 += lo2f((unsigned)rb.x); fs3 += hi2f((unsigned)rb.x);
                fs4 += lo2f((unsigned)rb.y); fs5 += hi2f((unsigned)rb.y);
                fs6 += lo2f((unsigned)rc.x); fs7 += hi2f((unsigned)rc.x);
                fs8 += lo2f((unsigned)rc.y);
            }
#pragma unroll
            for (int j = 0; j < 16; ++j) {
                int r = 4 * j + q;
                int s = __shfl(sid, r);
                if (r < m) {
                    int4 nv = nf16[(long)s * 16 + lp];
                    accA.x += lo2f((unsigned)nv.x); accA.y += hi2f((unsigned)nv.x);
                    accA.z += lo2f((unsigned)nv.y); accA.w += hi2f((unsigned)nv.y);
                    accB.x += lo2f((unsigned)nv.z); accB.y += hi2f((unsigned)nv.z);
                    accB.z += lo2f((unsigned)nv.w); accB.w += hi2f((unsigned)nv.w);
                }
            }
        }

        // reduce 4 quarter partials
        accA.x += __shfl_xor(accA.x, 16); accA.x += __shfl_xor(accA.x, 32);
        accA.y += __shfl_xor(accA.y, 16); accA.y += __shfl_xor(accA.y, 32);
        accA.z += __shfl_xor(accA.z, 16); accA.z += __shfl_xor(accA.z, 32);
        accA.w += __shfl_xor(accA.w, 16); accA.w += __shfl_xor(accA.w, 32);
        accB.x += __shfl_xor(accB.x, 16); accB.x += __shfl_xor(accB.x, 32);
        accB.y += __shfl_xor(accB.y, 16); accB.y += __shfl_xor(accB.y, 32);
        accB.z += __shfl_xor(accB.z, 16); accB.z += __shfl_xor(accB.z, 32);
        accB.w += __shfl_xor(accB.w, 16); accB.w += __shfl_xor(accB.w, 32);

#define WRED(v) v += __shfl_xor(v, 1); v += __shfl_xor(v, 2); v += __shfl_xor(v, 4); \
                v += __shfl_xor(v, 8); v += __shfl_xor(v, 16); v += __shfl_xor(v, 32);
        WRED(fs0) WRED(fs1) WRED(fs2) WRED(fs3) WRED(fs4)
        WRED(fs5) WRED(fs6) WRED(fs7) WRED(fs8)
#undef WRED

        if (q == 0) {
            float deg = (float)(end - beg);
            float4 bA = ((const float4*)be0)[2 * lp];
            float4 bB = ((const float4*)be0)[2 * lp + 1];
            float4 cA = ((const float4*)be1)[2 * lp];
            float4 cB = ((const float4*)be1)[2 * lp + 1];
            float4 eA, eB;
            eA.x = deg * (bA.x + cA.x); eA.y = deg * (bA.y + cA.y);
            eA.z = deg * (bA.z + cA.z); eA.w = deg * (bA.w + cA.w);
            eB.x = deg * (bB.x + cB.x); eB.y = deg * (bB.y + cB.y);
            eB.z = deg * (bB.z + cB.z); eB.w = deg * (bB.w + cB.w);
            float fk[9] = {fs0, fs1, fs2, fs3, fs4, fs5, fs6, fs7, fs8};
#pragma unroll
            for (int k = 0; k < 6; ++k) {
                float4 wA = ((const float4*)We0)[k * 32 + 2 * lp];
                float4 wB = ((const float4*)We0)[k * 32 + 2 * lp + 1];
                eA.x = fmaf(fk[k], wA.x, eA.x); eA.y = fmaf(fk[k], wA.y, eA.y);
                eA.z = fmaf(fk[k], wA.z, eA.z); eA.w = fmaf(fk[k], wA.w, eA.w);
                eB.x = fmaf(fk[k], wB.x, eB.x); eB.y = fmaf(fk[k], wB.y, eB.y);
                eB.z = fmaf(fk[k], wB.z, eB.z); eB.w = fmaf(fk[k], wB.w, eB.w);
            }
#pragma unroll
            for (int k = 0; k < 3; ++k) {
                float4 wA = ((const float4*)We1)[k * 32 + 2 * lp];
                float4 wB = ((const float4*)We1)[k * 32 + 2 * lp + 1];
                eA.x = fmaf(fk[6 + k], wA.x, eA.x); eA.y = fmaf(fk[6 + k], wA.y, eA.y);
                eA.z = fmaf(fk[6 + k], wA.z, eA.z); eA.w = fmaf(fk[6 + k], wA.w, eA.w);
                eB.x = fmaf(fk[6 + k], wB.x, eB.x); eB.y = fmaf(fk[6 + k], wB.y, eB.y);
                eB.z = fmaf(fk[6 + k], wB.z, eB.z); eB.w = fmaf(fk[6 + k], wB.w, eB.w);
            }
            union { ushort u[8]; short8 v; } pk;
            pk.u[0] = f2bf(accA.x + eA.x); pk.u[1] = f2bf(accA.y + eA.y);
            pk.u[2] = f2bf(accA.z + eA.z); pk.u[3] = f2bf(accA.w + eA.w);
            pk.u[4] = f2bf(accB.x + eB.x); pk.u[5] = f2bf(accB.y + eB.y);
            pk.u[6] = f2bf(accB.z + eB.z); pk.u[7] = f2bf(accB.w + eB.w);
            *(short8*)&aggS[row * 256 + ((lp * 16) ^ ((row & 7) << 4))] = pk.v;
        }
    }
    __syncthreads();

    // ---------------- phase 2: MFMA MLP from LDS ----------------
    short8 a[2][4];
#pragma unroll
    for (int mt = 0; mt < 2; ++mt)
#pragma unroll
        for (int ks = 0; ks < 4; ++ks) {
            int row = (lane & 15) + mt * 16;
            int kb = ks * 64 + ((lane >> 4) << 4);
            a[mt][ks] = *(const short8*)&aggS[row * 256 + (kb ^ ((row & 7) << 4))];
        }

    floatx4 acc1[2][4];
#pragma unroll
    for (int nt = 0; nt < 4; ++nt) {
        float bias = b1[(wv * 4 + nt) * 16 + (lane & 15)];
#pragma unroll
        for (int mt = 0; mt < 2; ++mt)
            acc1[mt][nt] = (floatx4){bias, bias, bias, bias};
    }
#pragma unroll
    for (int ks = 0; ks < 4; ++ks) {
#pragma unroll
        for (int nt = 0; nt < 4; ++nt) {
            short8 b = *(const short8*)&w1f[(((wv * 4 + nt) * 4 + ks) * 64 + lane) * 8];
            acc1[0][nt] = __builtin_amdgcn_mfma_f32_16x16x32_bf16(a[0][ks], b, acc1[0][nt], 0, 0, 0);
            acc1[1][nt] = __builtin_amdgcn_mfma_f32_16x16x32_bf16(a[1][ks], b, acc1[1][nt], 0, 0, 0);
        }
    }
#pragma unroll
    for (int mt = 0; mt < 2; ++mt)
#pragma unroll
        for (int nt = 0; nt < 4; ++nt)
#pragma unroll
            for (int i = 0; i < 4; ++i) {
                int row = mt * 16 + ((lane >> 4) << 2) + i;
                int col = (wv * 4 + nt) * 16 + (lane & 15);
                float v = fmaxf(acc1[mt][nt][i], 0.f);
                *(ushort*)&h1S[row * 512 + ((2 * col) ^ ((row & 7) << 4))] = f2bf(v);
            }
    __syncthreads();

    int swz = (lane & 7) << 4;
    floatx4 acc2[2][2];
#pragma unroll
    for (int nt = 0; nt < 2; ++nt) {
        float bias = b2[(wv * 2 + nt) * 16 + (lane & 15)];
#pragma unroll
        for (int mt = 0; mt < 2; ++mt)
            acc2[mt][nt] = (floatx4){bias, bias, bias, bias};
    }
#pragma unroll
    for (int ks = 0; ks < 8; ++ks) {
        int kb = ks * 64 + ((lane >> 4) << 4);
        short8 a0 = *(const short8*)&h1S[(lane & 15) * 512 + (kb ^ swz)];
        short8 a1 = *(const short8*)&h1S[(16 + (lane & 15)) * 512 + (kb ^ swz)];
#pragma unroll
        for (int nt = 0; nt < 2; ++nt) {
            short8 b = *(const short8*)&w2f[(((wv * 2 + nt) * 8 + ks) * 64 + lane) * 8];
            acc2[0][nt] = __builtin_amdgcn_mfma_f32_16x16x32_bf16(a0, b, acc2[0][nt], 0, 0, 0);
            acc2[1][nt] = __builtin_amdgcn_mfma_f32_16x16x32_bf16(a1, b, acc2[1][nt], 0, 0, 0);
        }
    }

    float s[2] = {0.f, 0.f}, s2[2] = {0.f, 0.f};
#pragma unroll
    for (int nt = 0; nt < 2; ++nt) {
        int col = (wv * 2 + nt) * 16 + (lane & 15);
#pragma unroll
        for (int mt = 0; mt < 2; ++mt)
#pragma unroll
            for (int i = 0; i < 4; ++i) {
                int row = mt * 16 + ((lane >> 4) << 2) + i;
                float v = acc2[mt][nt][i];
                h[(nbase + row) * EMB + col] = v;
                s[nt] += v;
                s2[nt] = fmaf(v, v, s2[nt]);
            }
    }
#pragma unroll
    for (int nt = 0; nt < 2; ++nt) {
        s[nt] += __shfl_xor(s[nt], 16);
        s[nt] += __shfl_xor(s[nt], 32);
        s2[nt] += __shfl_xor(s2[nt], 16);
        s2[nt] += __shfl_xor(s2[nt], 32);
    }
    if (lane < 16) {
        float* slab = stats + (blockIdx.x & (NSLAB - 1)) * (2 * EMB);
#pragma unroll
        for (int nt = 0; nt < 2; ++nt) {
            int col = (wv * 2 + nt) * 16 + lane;
            atomicAdd(&slab[col], s[nt]);
            atomicAdd(&slab[EMB + col], s2[nt]);
        }
    }
}

// =================== LAST resort: atomic path ===================
__global__ __launch_bounds__(256) void edge_scatter_kernel(
    const float* __restrict__ node_feats,
    const float* __restrict__ ef0,
    const float* __restrict__ ef1,
    const int* __restrict__ src,
    const int* __restrict__ dst,
    const float* __restrict__ We0, const float* __restrict__ be0,
    const float* __restrict__ We1, const float* __restrict__ be1,
    float* __restrict__ agg)
{
    __shared__ float wS[10 * EMB];
    int tid = threadIdx.x;
    for (int i = tid; i < 6 * EMB; i += 256) wS[i] = We0[i];
    for (int i = tid; i < 3 * EMB; i += 256) wS[6 * EMB + i] = We1[i];
    if (tid < EMB) wS[9 * EMB + tid] = be0[tid] + be1[tid];
    __syncthreads();

    int e = blockIdx.x * 2 + (tid >> 7);
    if (e >= N_EDGES) return;
    int d = tid & 127;
    int s = src[e];
    int t = dst[e];
    const float* f0 = ef0 + (long)e * 6;
    const float* f1 = ef1 + (long)e * 3;

    float emb = wS[9 * EMB + d];
#pragma unroll
    for (int k = 0; k < 6; ++k) emb = fmaf(f0[k], wS[k * EMB + d], emb);
#pragma unroll
    for (int k = 0; k < 3; ++k) emb = fmaf(f1[k], wS[6 * EMB + k * EMB + d], emb);

    float val = node_feats[(long)s * EMB + d] + emb;
    atomicAdd(&agg[(long)t * EMB + d], val);
}

// =================== fp32 MLP fallback (atomic tier only) ===================
__global__ __launch_bounds__(256) void mlp_kernel(
    float* __restrict__ h,
    const float* __restrict__ W1, const float* __restrict__ b1,
    const float* __restrict__ W2, const float* __restrict__ b2,
    float* __restrict__ stats)
{
    __shared__ float aggS[BM][EMB];
    __shared__ float h1S[BM][2 * EMB];
    __shared__ float sredS[256];
    __shared__ float s2redS[256];

    int tid = threadIdx.x;
    long base = (long)blockIdx.x * BM;

    for (int i = tid; i < BM * EMB; i += 256)
        aggS[i >> 7][i & 127] = h[base * EMB + i];
    __syncthreads();

    {
        float acc[BM];
        float bias = b1[tid];
#pragma unroll
        for (int r = 0; r < BM; ++r) acc[r] = bias;
        for (int k = 0; k < EMB; ++k) {
            float w = W1[k * (2 * EMB) + tid];
#pragma unroll
            for (int r = 0; r < BM; ++r) acc[r] = fmaf(aggS[r][k], w, acc[r]);
        }
#pragma unroll
        for (int r = 0; r < BM; ++r) h1S[r][tid] = fmaxf(acc[r], 0.0f);
    }
    __syncthreads();

    {
        int c = tid & 127;
        int half = tid >> 7;
        float acc[8];
        float bias = b2[c];
#pragma unroll
        for (int r = 0; r < 8; ++r) acc[r] = bias;
        for (int k = 0; k < 2 * EMB; ++k) {
            float w = W2[k * EMB + c];
#pragma unroll
            for (int r = 0; r < 8; ++r) acc[r] = fmaf(h1S[half * 8 + r][k], w, acc[r]);
        }
        float s = 0.f, s2 = 0.f;
#pragma unroll
        for (int r = 0; r < 8; ++r) {
            h[(base + half * 8 + r) * EMB + c] = acc[r];
            s += acc[r];
            s2 = fmaf(acc[r], acc[r], s2);
        }
        sredS[tid] = s;
        s2redS[tid] = s2;
    }
    __syncthreads();
    if (tid < 128) {
        float s = sredS[tid] + sredS[tid + 128];
        float s2 = s2redS[tid] + s2redS[tid + 128];
        float* slab = stats + (blockIdx.x & (NSLAB - 1)) * (2 * EMB);
        atomicAdd(&slab[tid], s);
        atomicAdd(&slab[EMB + tid], s2);
    }
}

// =================== BN apply (derives scale/shift per block) ===============
__global__ __launch_bounds__(256) void bn_apply_fused_kernel(
    float* __restrict__ h, const float* __restrict__ stats,
    const float* __restrict__ gamma, const float* __restrict__ beta)
{
    __shared__ float scS[EMB], shS[EMB];
    int tid = threadIdx.x;
    if (tid < EMB) {
        float s = 0.f, s2 = 0.f;
        for (int b = 0; b < NSLAB; ++b) {
            s += stats[b * (2 * EMB) + tid];
            s2 += stats[b * (2 * EMB) + EMB + tid];
        }
        float mean = s / (float)N_NODES;
        float var = s2 / (float)N_NODES - mean * mean;
        float sc = gamma[tid] * rsqrtf(var + BN_EPS);
        scS[tid] = sc;
        shS[tid] = beta[tid] - mean * sc;
    }
    __syncthreads();
    long total = (long)N_NODES * EMB / 4;
    long stride = (long)gridDim.x * blockDim.x;
    for (long i = (long)blockIdx.x * blockDim.x + threadIdx.x; i < total; i += stride) {
        float4 v = ((float4*)h)[i];
        int c = (int)((i * 4) & 127);
        v.x = fmaf(v.x, scS[c + 0], shS[c + 0]);
        v.y = fmaf(v.y, scS[c + 1], shS[c + 1]);
        v.z = fmaf(v.z, scS[c + 2], shS[c + 2]);
        v.w = fmaf(v.w, scS[c + 3], shS[c + 3]);
        ((float4*)h)[i] = v;
    }
}

extern "C" void kernel_launch(void* const* d_in, const int* in_sizes, int n_in,
                              void* d_out, int out_size, void* d_ws, size_t ws_size,
                              hipStream_t stream) {
    const float* node_feats = (const float*)d_in[0];
    const float* ef0 = (const float*)d_in[1];
    const float* ef1 = (const float*)d_in[2];
    const int* src = (const int*)d_in[3];
    const int* dst = (const int*)d_in[4];
    const float* We0 = (const float*)d_in[5];
    const float* be0 = (const float*)d_in[6];
    const float* We1 = (const float*)d_in[7];
    const float* be1 = (const float*)d_in[8];
    const float* W1 = (const float*)d_in[9];
    const float* b1 = (const float*)d_in[10];
    const float* W2 = (const float*)d_in[11];
    const float* b2 = (const float*)d_in[12];
    const float* gamma = (const float*)d_in[13];
    const float* beta = (const float*)d_in[14];

    float* out = (float*)d_out;

    // ws layout (65,402,880 B == proven-available footprint)
    float* stats = (float*)d_ws;                          // 65536 B
    float* scaleshift = stats + NSLAB * 2 * EMB;          // 1024 B (layout pad)
    int* counts = (int*)(scaleshift + 256);               // NPAD ints
    int* offsets = counts + NPAD;                         // NPAD ints
    int* cursor = offsets + NPAD;                         // NPAD ints
    int* blockSums = cursor + NPAD;                       // 1024 B
    ushort* w1f = (ushort*)(blockSums + 256);             // 64 KB
    ushort* w2f = w1f + 32768;                            // 64 KB
    int* rec24 = (int*)(w2f + 32768);                     // E*24 B (38.4 MB)
    ushort* nfbf = (ushort*)(rec24 + (size_t)N_EDGES * 6);// N*128 bf16 (25.6 MB)
    size_t needed = (size_t)((char*)(nfbf + (size_t)N_NODES * EMB) - (char*)d_ws);

    if (ws_size >= needed) {
        hipMemsetAsync(d_ws, 0,
            (size_t)(NSLAB * 2 * EMB + 256) * sizeof(float) + (size_t)NPAD * sizeof(int),
            stream);
        setup_kernel<<<2048, 256, 0, stream>>>(
            node_feats, nfbf, dst, counts, W1, W2, w1f, w2f);
        scan_blocksum_kernel<<<NB_SCAN, SCAN_BLK, 0, stream>>>(counts, blockSums);
        scan_final_kernel<<<NB_SCAN, SCAN_BLK, 0, stream>>>(counts, blockSums, offsets, cursor);
        scatter24_kernel<<<(N_EDGES + 255) / 256, 256, 0, stream>>>(
            src, dst, ef0, ef1, cursor, rec24);
        gather_mlp_kernel<<<N_NODES / 32, 256, 0, stream>>>(
            nfbf, rec24, offsets, We0, be0, We1, be1, w1f, w2f, b1, b2, out, stats);
    } else {
        hipMemsetAsync(stats, 0, (size_t)NSLAB * 2 * EMB * sizeof(float), stream);
        hipMemsetAsync(d_out, 0, (size_t)N_NODES * EMB * sizeof(float), stream);
        edge_scatter_kernel<<<N_EDGES / 2, 256, 0, stream>>>(
            node_feats, ef0, ef1, src, dst, We0, be0, We1, be1, out);
        mlp_kernel<<<N_NODES / BM, 256, 0, stream>>>(out, W1, b1, W2, b2, stats);
    }

    bn_apply_fused_kernel<<<4096, 256, 0, stream>>>(out, stats, gamma, beta);
}

// Round 10
// 348.098 us; speedup vs baseline: 1.3322x; 1.3322x over previous
//
#include <hip/hip_runtime.h>

#define N_NODES 100000
#define N_EDGES 1600000
#define EMB 128
#define BM 16
#define NSLAB 64
#define BN_EPS 1e-5f

#define SCAN_BLK 512
#define NB_SCAN ((N_NODES + SCAN_BLK - 1) / SCAN_BLK)   // 196
#define NPAD (NB_SCAN * SCAN_BLK)                       // 100352

typedef short short8 __attribute__((ext_vector_type(8)));
typedef float floatx4 __attribute__((ext_vector_type(4)));

__device__ __forceinline__ ushort f2bf(float x) {
    unsigned u = __float_as_uint(x);
    u += 0x7fffu + ((u >> 16) & 1u);   // RNE
    return (ushort)(u >> 16);
}
__device__ __forceinline__ float lo2f(unsigned p) {    // low bf16 of packed u32
    return __uint_as_float(p << 16);
}
__device__ __forceinline__ float hi2f(unsigned p) {    // high bf16 of packed u32
    return __uint_as_float(p & 0xffff0000u);
}

// DPP-based full-wave sum on the VALU pipe (no ds_bpermute):
// row_shr 1/2/4/8 -> per-16-row sums in lanes 15/31/47/63;
// row_bcast15 (rows 1,3) + row_bcast31 (rows 2,3) -> grand total in lane 63.
#define DPP_ADD(x, ctrl, mask) \
    ((x) + __int_as_float(__builtin_amdgcn_update_dpp(0, __float_as_int(x), ctrl, mask, 0xf, true)))

__device__ __forceinline__ float wave_sum63(float x) {
    x = DPP_ADD(x, 0x111, 0xf);   // row_shr:1
    x = DPP_ADD(x, 0x112, 0xf);   // row_shr:2
    x = DPP_ADD(x, 0x114, 0xf);   // row_shr:4
    x = DPP_ADD(x, 0x118, 0xf);   // row_shr:8
    x = DPP_ADD(x, 0x142, 0xa);   // row_bcast15 -> rows 1,3
    x = DPP_ADD(x, 0x143, 0xc);   // row_bcast31 -> rows 2,3
    return __int_as_float(__builtin_amdgcn_readlane(__float_as_int(x), 63));
}

// =================== setup: nf->bf16 + dst histogram + weight frags =========
__global__ __launch_bounds__(256) void setup_kernel(
    const float* __restrict__ nf, ushort* __restrict__ nfbf,
    const int* __restrict__ dst, int* __restrict__ counts,
    const float* __restrict__ W1, const float* __restrict__ W2,
    ushort* __restrict__ w1f, ushort* __restrict__ w2f)
{
    int gtid = blockIdx.x * 256 + threadIdx.x;
    long gstride = (long)gridDim.x * 256;

    if (gtid < 65536) {
        int idx = gtid;
        int i = idx & 7;
        int lane = (idx >> 3) & 63;
        int kloc = ((lane >> 4) << 3) + i;
        int nloc = lane & 15;
        if (idx < 32768) {
            int ks = (idx >> 9) & 3, nt = idx >> 11;
            w1f[idx] = f2bf(W1[(ks * 32 + kloc) * 256 + nt * 16 + nloc]);
        } else {
            int j = idx - 32768;
            int ks = (j >> 9) & 7, nt = j >> 12;
            w2f[j] = f2bf(W2[(ks * 32 + kloc) * 128 + nt * 16 + nloc]);
        }
    }

    long total = (long)N_NODES * EMB / 4;
    for (long p = gtid; p < total; p += gstride) {
        float4 v = ((const float4*)nf)[p];
        ushort4 o;
        o.x = f2bf(v.x); o.y = f2bf(v.y); o.z = f2bf(v.z); o.w = f2bf(v.w);
        ((ushort4*)nfbf)[p] = o;
    }

    for (long e = gtid; e < N_EDGES; e += gstride)
        atomicAdd(&counts[dst[e]], 1);
}

// =================== scan machinery (2 kernels) ===================
__global__ __launch_bounds__(SCAN_BLK) void scan_blocksum_kernel(
    const int* __restrict__ counts, int* __restrict__ blockSums)
{
    __shared__ int red[SCAN_BLK];
    int t = threadIdx.x;
    int i = blockIdx.x * SCAN_BLK + t;
    red[t] = (i < N_NODES) ? counts[i] : 0;
    __syncthreads();
    for (int s = SCAN_BLK / 2; s > 0; s >>= 1) {
        if (t < s) red[t] += red[t + s];
        __syncthreads();
    }
    if (t == 0) blockSums[blockIdx.x] = red[0];
}

// scans blockSums locally (196 entries) AND the per-element counts
__global__ __launch_bounds__(SCAN_BLK) void scan_final_kernel(
    const int* __restrict__ counts, const int* __restrict__ blockSums,
    int* __restrict__ offsets, int* __restrict__ cursor)
{
    __shared__ int s[SCAN_BLK];
    __shared__ int bs[256];
    int t = threadIdx.x;
    if (t < 256) bs[t] = (t < NB_SCAN) ? blockSums[t] : 0;
    __syncthreads();
    for (int off = 1; off < 256; off <<= 1) {
        int v = (t < 256 && t >= off) ? bs[t - off] : 0;
        __syncthreads();
        if (t < 256) bs[t] += v;
        __syncthreads();
    }
    int blockBase = (blockIdx.x == 0) ? 0 : bs[blockIdx.x - 1];

    int i = blockIdx.x * SCAN_BLK + t;
    int orig = (i < N_NODES) ? counts[i] : 0;
    s[t] = orig;
    __syncthreads();
    for (int off = 1; off < SCAN_BLK; off <<= 1) {
        int v = (t >= off) ? s[t - off] : 0;
        __syncthreads();
        s[t] += v;
        __syncthreads();
    }
    int excl = s[t] - orig + blockBase;
    if (i < N_NODES) { offsets[i] = excl; cursor[i] = excl; }
    if (i == N_NODES) offsets[N_NODES] = N_EDGES;
}

// =================== scatter: 24B records {src, 9xbf16} sorted by dst =======
__global__ __launch_bounds__(256) void scatter24_kernel(
    const int* __restrict__ src, const int* __restrict__ dst,
    const float* __restrict__ ef0, const float* __restrict__ ef1,
    int* __restrict__ cursor, int* __restrict__ rec24)
{
    int e = blockIdx.x * 256 + threadIdx.x;
    if (e >= N_EDGES) return;
    int t = dst[e];
    int pos = atomicAdd(&cursor[t], 1);

    const float2* p0 = (const float2*)(ef0 + (long)e * 6);
    float2 q0 = p0[0], q1 = p0[1], q2 = p0[2];
    const float* p1 = ef1 + (long)e * 3;
    float g0 = p1[0], g1 = p1[1], g2 = p1[2];

    unsigned u0 = (unsigned)f2bf(q0.x) | ((unsigned)f2bf(q0.y) << 16);
    unsigned u1 = (unsigned)f2bf(q1.x) | ((unsigned)f2bf(q1.y) << 16);
    unsigned u2 = (unsigned)f2bf(q2.x) | ((unsigned)f2bf(q2.y) << 16);
    unsigned u3 = (unsigned)f2bf(g0)   | ((unsigned)f2bf(g1) << 16);
    unsigned u4 = (unsigned)f2bf(g2);

    int2* out = (int2*)(rec24 + (long)pos * 6);
    out[0] = make_int2(src[e], (int)u0);
    out[1] = make_int2((int)u1, (int)u2);
    out[2] = make_int2((int)u3, (int)u4);
}

// =================== gather: 4 rows in flight, DPP reductions ===============
__global__ __launch_bounds__(256, 8) void gather4_kernel(
    const ushort* __restrict__ nfbf, const int* __restrict__ rec24,
    const int* __restrict__ offsets,
    const float* __restrict__ We0, const float* __restrict__ be0,
    const float* __restrict__ We1, const float* __restrict__ be1,
    float* __restrict__ agg)
{
    int wv = threadIdx.x >> 6, lane = threadIdx.x & 63;
    int n = blockIdx.x * 4 + wv;
    if (n >= N_NODES) return;
    int q = lane >> 4, lp = lane & 15;

    int beg = offsets[n], end = offsets[n + 1];
    float4 accA = make_float4(0.f, 0.f, 0.f, 0.f);
    float4 accB = make_float4(0.f, 0.f, 0.f, 0.f);
    float fs0 = 0.f, fs1 = 0.f, fs2 = 0.f, fs3 = 0.f, fs4 = 0.f,
          fs5 = 0.f, fs6 = 0.f, fs7 = 0.f, fs8 = 0.f;
    const int4* nf16 = (const int4*)nfbf;   // row = 16 int4

    int base = beg;
    // full chunks (deg >= 64)
    for (; base + 64 <= end; base += 64) {
        const int2* rp = (const int2*)(rec24 + (long)(base + lane) * 6);
        int2 ra = rp[0], rb = rp[1], rc = rp[2];
        int sid = ra.x;
        fs0 += lo2f((unsigned)ra.y); fs1 += hi2f((unsigned)ra.y);
        fs2 += lo2f((unsigned)rb.x); fs3 += hi2f((unsigned)rb.x);
        fs4 += lo2f((unsigned)rb.y); fs5 += hi2f((unsigned)rb.y);
        fs6 += lo2f((unsigned)rc.x); fs7 += hi2f((unsigned)rc.x);
        fs8 += lo2f((unsigned)rc.y);
#pragma unroll 4
        for (int j = 0; j < 16; ++j) {
            int s = __shfl(sid, 4 * j + q);
            int4 nv = nf16[(long)s * 16 + lp];
            accA.x += lo2f((unsigned)nv.x); accA.y += hi2f((unsigned)nv.x);
            accA.z += lo2f((unsigned)nv.y); accA.w += hi2f((unsigned)nv.y);
            accB.x += lo2f((unsigned)nv.z); accB.y += hi2f((unsigned)nv.z);
            accB.z += lo2f((unsigned)nv.w); accB.w += hi2f((unsigned)nv.w);
        }
    }
    // tail: rounds gated by the wave-uniform count (deg-16 node -> 4 rounds)
    if (base < end) {
        int m = end - base;
        int sid = 0;
        if (lane < m) {
            const int2* rp = (const int2*)(rec24 + (long)(base + lane) * 6);
            int2 ra = rp[0], rb = rp[1], rc = rp[2];
            sid = ra.x;
            fs0 += lo2f((unsigned)ra.y); fs1 += hi2f((unsigned)ra.y);
            fs2 += lo2f((unsigned)rb.x); fs3 += hi2f((unsigned)rb.x);
            fs4 += lo2f((unsigned)rb.y); fs5 += hi2f((unsigned)rb.y);
            fs6 += lo2f((unsigned)rc.x); fs7 += hi2f((unsigned)rc.x);
            fs8 += lo2f((unsigned)rc.y);
        }
        int rounds = (m + 3) >> 2;
#pragma unroll 4
        for (int j = 0; j < rounds; ++j) {
            int r = 4 * j + q;
            int s = __shfl(sid, r);
            if (r < m) {
                int4 nv = nf16[(long)s * 16 + lp];
                accA.x += lo2f((unsigned)nv.x); accA.y += hi2f((unsigned)nv.x);
                accA.z += lo2f((unsigned)nv.y); accA.w += hi2f((unsigned)nv.y);
                accB.x += lo2f((unsigned)nv.z); accB.y += hi2f((unsigned)nv.z);
                accB.z += lo2f((unsigned)nv.w); accB.w += hi2f((unsigned)nv.w);
            }
        }
    }

    // reduce the 4 quarter partials (cross-quarter: xor16 + xor32)
    accA.x += __shfl_xor(accA.x, 16); accA.x += __shfl_xor(accA.x, 32);
    accA.y += __shfl_xor(accA.y, 16); accA.y += __shfl_xor(accA.y, 32);
    accA.z += __shfl_xor(accA.z, 16); accA.z += __shfl_xor(accA.z, 32);
    accA.w += __shfl_xor(accA.w, 16); accA.w += __shfl_xor(accA.w, 32);
    accB.x += __shfl_xor(accB.x, 16); accB.x += __shfl_xor(accB.x, 32);
    accB.y += __shfl_xor(accB.y, 16); accB.y += __shfl_xor(accB.y, 32);
    accB.z += __shfl_xor(accB.z, 16); accB.z += __shfl_xor(accB.z, 32);
    accB.w += __shfl_xor(accB.w, 16); accB.w += __shfl_xor(accB.w, 32);

    // 9 feature sums: DPP chains on the VALU pipe -> uniform scalars
    float fk0 = wave_sum63(fs0), fk1 = wave_sum63(fs1), fk2 = wave_sum63(fs2);
    float fk3 = wave_sum63(fs3), fk4 = wave_sum63(fs4), fk5 = wave_sum63(fs5);
    float fk6 = wave_sum63(fs6), fk7 = wave_sum63(fs7), fk8 = wave_sum63(fs8);

    if (q == 0) {
        float deg = (float)(end - beg);
        float4 bA = ((const float4*)be0)[2 * lp];
        float4 bB = ((const float4*)be0)[2 * lp + 1];
        float4 cA = ((const float4*)be1)[2 * lp];
        float4 cB = ((const float4*)be1)[2 * lp + 1];
        float4 eA, eB;
        eA.x = deg * (bA.x + cA.x); eA.y = deg * (bA.y + cA.y);
        eA.z = deg * (bA.z + cA.z); eA.w = deg * (bA.w + cA.w);
        eB.x = deg * (bB.x + cB.x); eB.y = deg * (bB.y + cB.y);
        eB.z = deg * (bB.z + cB.z); eB.w = deg * (bB.w + cB.w);
        float fk[9] = {fk0, fk1, fk2, fk3, fk4, fk5, fk6, fk7, fk8};
#pragma unroll
        for (int k = 0; k < 6; ++k) {
            float4 wA = ((const float4*)We0)[k * 32 + 2 * lp];
            float4 wB = ((const float4*)We0)[k * 32 + 2 * lp + 1];
            eA.x = fmaf(fk[k], wA.x, eA.x); eA.y = fmaf(fk[k], wA.y, eA.y);
            eA.z = fmaf(fk[k], wA.z, eA.z); eA.w = fmaf(fk[k], wA.w, eA.w);
            eB.x = fmaf(fk[k], wB.x, eB.x); eB.y = fmaf(fk[k], wB.y, eB.y);
            eB.z = fmaf(fk[k], wB.z, eB.z); eB.w = fmaf(fk[k], wB.w, eB.w);
        }
#pragma unroll
        for (int k = 0; k < 3; ++k) {
            float4 wA = ((const float4*)We1)[k * 32 + 2 * lp];
            float4 wB = ((const float4*)We1)[k * 32 + 2 * lp + 1];
            eA.x = fmaf(fk[6 + k], wA.x, eA.x); eA.y = fmaf(fk[6 + k], wA.y, eA.y);
            eA.z = fmaf(fk[6 + k], wA.z, eA.z); eA.w = fmaf(fk[6 + k], wA.w, eA.w);
            eB.x = fmaf(fk[6 + k], wB.x, eB.x); eB.y = fmaf(fk[6 + k], wB.y, eB.y);
            eB.z = fmaf(fk[6 + k], wB.z, eB.z); eB.w = fmaf(fk[6 + k], wB.w, eB.w);
        }
        float4 oA = make_float4(accA.x + eA.x, accA.y + eA.y, accA.z + eA.z, accA.w + eA.w);
        float4 oB = make_float4(accB.x + eB.x, accB.y + eB.y, accB.z + eB.z, accB.w + eB.w);
        ((float4*)agg)[(long)n * 32 + 2 * lp] = oA;
        ((float4*)agg)[(long)n * 32 + 2 * lp + 1] = oB;
    }
}

// =================== LAST resort: atomic path ===================
__global__ __launch_bounds__(256) void edge_scatter_kernel(
    const float* __restrict__ node_feats,
    const float* __restrict__ ef0,
    const float* __restrict__ ef1,
    const int* __restrict__ src,
    const int* __restrict__ dst,
    const float* __restrict__ We0, const float* __restrict__ be0,
    const float* __restrict__ We1, const float* __restrict__ be1,
    float* __restrict__ agg)
{
    __shared__ float wS[10 * EMB];
    int tid = threadIdx.x;
    for (int i = tid; i < 6 * EMB; i += 256) wS[i] = We0[i];
    for (int i = tid; i < 3 * EMB; i += 256) wS[6 * EMB + i] = We1[i];
    if (tid < EMB) wS[9 * EMB + tid] = be0[tid] + be1[tid];
    __syncthreads();

    int e = blockIdx.x * 2 + (tid >> 7);
    if (e >= N_EDGES) return;
    int d = tid & 127;
    int s = src[e];
    int t = dst[e];
    const float* f0 = ef0 + (long)e * 6;
    const float* f1 = ef1 + (long)e * 3;

    float emb = wS[9 * EMB + d];
#pragma unroll
    for (int k = 0; k < 6; ++k) emb = fmaf(f0[k], wS[k * EMB + d], emb);
#pragma unroll
    for (int k = 0; k < 3; ++k) emb = fmaf(f1[k], wS[6 * EMB + k * EMB + d], emb);

    float val = node_feats[(long)s * EMB + d] + emb;
    atomicAdd(&agg[(long)t * EMB + d], val);
}

// =================== fused MFMA MLP + BN stats (A from fp32 d_out, in-place) =
__global__ __launch_bounds__(256) void mlp_mfma_kernel(
    float* __restrict__ h,
    const ushort* __restrict__ w1f, const ushort* __restrict__ w2f,
    const float* __restrict__ b1, const float* __restrict__ b2,
    float* __restrict__ stats)
{
    __shared__ __align__(16) char h1S[32 * 512];    // 32 rows x 256 bf16, swizzled

    int tid = threadIdx.x;
    int lane = tid & 63;
    int wv = tid >> 6;
    long base = (long)blockIdx.x * 32;

    // ---- A fragments from global fp32 (convert in reg) ----
    float4 araw[2][4][2];
#pragma unroll
    for (int mt = 0; mt < 2; ++mt)
#pragma unroll
        for (int ks = 0; ks < 4; ++ks) {
            long row = base + mt * 16 + (lane & 15);
            const float4* p = (const float4*)(h + row * EMB + ks * 32 + ((lane >> 4) << 3));
            araw[mt][ks][0] = p[0];
            araw[mt][ks][1] = p[1];
        }
    __syncthreads();   // all waves' A loads complete before any h store below

    short8 a[2][4];
#pragma unroll
    for (int mt = 0; mt < 2; ++mt)
#pragma unroll
        for (int ks = 0; ks < 4; ++ks) {
            union { ushort u[8]; short8 v; } pk;
            float4 x = araw[mt][ks][0], y = araw[mt][ks][1];
            pk.u[0] = f2bf(x.x); pk.u[1] = f2bf(x.y); pk.u[2] = f2bf(x.z); pk.u[3] = f2bf(x.w);
            pk.u[4] = f2bf(y.x); pk.u[5] = f2bf(y.y); pk.u[6] = f2bf(y.z); pk.u[7] = f2bf(y.w);
            a[mt][ks] = pk.v;
        }

    // ---- GEMM1: wave wv owns n-tiles [wv*4, wv*4+4) ----
    floatx4 acc1[2][4];
#pragma unroll
    for (int nt = 0; nt < 4; ++nt) {
        float bias = b1[(wv * 4 + nt) * 16 + (lane & 15)];
#pragma unroll
        for (int mt = 0; mt < 2; ++mt)
            acc1[mt][nt] = (floatx4){bias, bias, bias, bias};
    }
#pragma unroll
    for (int ks = 0; ks < 4; ++ks) {
#pragma unroll
        for (int nt = 0; nt < 4; ++nt) {
            short8 b = *(const short8*)&w1f[(((wv * 4 + nt) * 4 + ks) * 64 + lane) * 8];
            acc1[0][nt] = __builtin_amdgcn_mfma_f32_16x16x32_bf16(a[0][ks], b, acc1[0][nt], 0, 0, 0);
            acc1[1][nt] = __builtin_amdgcn_mfma_f32_16x16x32_bf16(a[1][ks], b, acc1[1][nt], 0, 0, 0);
        }
    }
    // relu -> bf16 -> h1S (swizzled)
#pragma unroll
    for (int mt = 0; mt < 2; ++mt)
#pragma unroll
        for (int nt = 0; nt < 4; ++nt)
#pragma unroll
            for (int i = 0; i < 4; ++i) {
                int row = mt * 16 + ((lane >> 4) << 2) + i;
                int col = (wv * 4 + nt) * 16 + (lane & 15);
                float v = fmaxf(acc1[mt][nt][i], 0.f);
                *(ushort*)&h1S[row * 512 + ((2 * col) ^ ((row & 7) << 4))] = f2bf(v);
            }
    __syncthreads();

    // ---- GEMM2: wave wv owns n-tiles [wv*2, wv*2+2) ----
    int swz = (lane & 7) << 4;
    floatx4 acc2[2][2];
#pragma unroll
    for (int nt = 0; nt < 2; ++nt) {
        float bias = b2[(wv * 2 + nt) * 16 + (lane & 15)];
#pragma unroll
        for (int mt = 0; mt < 2; ++mt)
            acc2[mt][nt] = (floatx4){bias, bias, bias, bias};
    }
#pragma unroll
    for (int ks = 0; ks < 8; ++ks) {
        int kb = ks * 64 + ((lane >> 4) << 4);
        short8 a0 = *(const short8*)&h1S[(lane & 15) * 512 + (kb ^ swz)];
        short8 a1 = *(const short8*)&h1S[(16 + (lane & 15)) * 512 + (kb ^ swz)];
#pragma unroll
        for (int nt = 0; nt < 2; ++nt) {
            short8 b = *(const short8*)&w2f[(((wv * 2 + nt) * 8 + ks) * 64 + lane) * 8];
            acc2[0][nt] = __builtin_amdgcn_mfma_f32_16x16x32_bf16(a0, b, acc2[0][nt], 0, 0, 0);
            acc2[1][nt] = __builtin_amdgcn_mfma_f32_16x16x32_bf16(a1, b, acc2[1][nt], 0, 0, 0);
        }
    }

    // ---- epilogue: store + per-column stats ----
    float s[2] = {0.f, 0.f}, s2[2] = {0.f, 0.f};
#pragma unroll
    for (int nt = 0; nt < 2; ++nt) {
        int col = (wv * 2 + nt) * 16 + (lane & 15);
#pragma unroll
        for (int mt = 0; mt < 2; ++mt)
#pragma unroll
            for (int i = 0; i < 4; ++i) {
                int row = mt * 16 + ((lane >> 4) << 2) + i;
                float v = acc2[mt][nt][i];
                h[(base + row) * EMB + col] = v;
                s[nt] += v;
                s2[nt] = fmaf(v, v, s2[nt]);
            }
    }
#pragma unroll
    for (int nt = 0; nt < 2; ++nt) {
        s[nt] += __shfl_xor(s[nt], 16);
        s[nt] += __shfl_xor(s[nt], 32);
        s2[nt] += __shfl_xor(s2[nt], 16);
        s2[nt] += __shfl_xor(s2[nt], 32);
    }
    if (lane < 16) {
        float* slab = stats + (blockIdx.x & (NSLAB - 1)) * (2 * EMB);
#pragma unroll
        for (int nt = 0; nt < 2; ++nt) {
            int col = (wv * 2 + nt) * 16 + lane;
            atomicAdd(&slab[col], s[nt]);
            atomicAdd(&slab[EMB + col], s2[nt]);
        }
    }
}

// =================== fp32 MLP fallback (atomic tier only) ===================
__global__ __launch_bounds__(256) void mlp_kernel(
    float* __restrict__ h,
    const float* __restrict__ W1, const float* __restrict__ b1,
    const float* __restrict__ W2, const float* __restrict__ b2,
    float* __restrict__ stats)
{
    __shared__ float aggS[BM][EMB];
    __shared__ float h1S[BM][2 * EMB];
    __shared__ float sredS[256];
    __shared__ float s2redS[256];

    int tid = threadIdx.x;
    long base = (long)blockIdx.x * BM;

    for (int i = tid; i < BM * EMB; i += 256)
        aggS[i >> 7][i & 127] = h[base * EMB + i];
    __syncthreads();

    {
        float acc[BM];
        float bias = b1[tid];
#pragma unroll
        for (int r = 0; r < BM; ++r) acc[r] = bias;
        for (int k = 0; k < EMB; ++k) {
            float w = W1[k * (2 * EMB) + tid];
#pragma unroll
            for (int r = 0; r < BM; ++r) acc[r] = fmaf(aggS[r][k], w, acc[r]);
        }
#pragma unroll
        for (int r = 0; r < BM; ++r) h1S[r][tid] = fmaxf(acc[r], 0.0f);
    }
    __syncthreads();

    {
        int c = tid & 127;
        int half = tid >> 7;
        float acc[8];
        float bias = b2[c];
#pragma unroll
        for (int r = 0; r < 8; ++r) acc[r] = bias;
        for (int k = 0; k < 2 * EMB; ++k) {
            float w = W2[k * EMB + c];
#pragma unroll
            for (int r = 0; r < 8; ++r) acc[r] = fmaf(h1S[half * 8 + r][k], w, acc[r]);
        }
        float s = 0.f, s2 = 0.f;
#pragma unroll
        for (int r = 0; r < 8; ++r) {
            h[(base + half * 8 + r) * EMB + c] = acc[r];
            s += acc[r];
            s2 = fmaf(acc[r], acc[r], s2);
        }
        sredS[tid] = s;
        s2redS[tid] = s2;
    }
    __syncthreads();
    if (tid < 128) {
        float s = sredS[tid] + sredS[tid + 128];
        float s2 = s2redS[tid] + s2redS[tid + 128];
        float* slab = stats + (blockIdx.x & (NSLAB - 1)) * (2 * EMB);
        atomicAdd(&slab[tid], s);
        atomicAdd(&slab[EMB + tid], s2);
    }
}

// =================== BN apply (derives scale/shift per block) ===============
__global__ __launch_bounds__(256) void bn_apply_fused_kernel(
    float* __restrict__ h, const float* __restrict__ stats,
    const float* __restrict__ gamma, const float* __restrict__ beta)
{
    __shared__ float scS[EMB], shS[EMB];
    int tid = threadIdx.x;
    if (tid < EMB) {
        float s = 0.f, s2 = 0.f;
        for (int b = 0; b < NSLAB; ++b) {
            s += stats[b * (2 * EMB) + tid];
            s2 += stats[b * (2 * EMB) + EMB + tid];
        }
        float mean = s / (float)N_NODES;
        float var = s2 / (float)N_NODES - mean * mean;
        float sc = gamma[tid] * rsqrtf(var + BN_EPS);
        scS[tid] = sc;
        shS[tid] = beta[tid] - mean * sc;
    }
    __syncthreads();
    long total = (long)N_NODES * EMB / 4;
    long stride = (long)gridDim.x * blockDim.x;
    for (long i = (long)blockIdx.x * blockDim.x + threadIdx.x; i < total; i += stride) {
        float4 v = ((float4*)h)[i];
        int c = (int)((i * 4) & 127);
        v.x = fmaf(v.x, scS[c + 0], shS[c + 0]);
        v.y = fmaf(v.y, scS[c + 1], shS[c + 1]);
        v.z = fmaf(v.z, scS[c + 2], shS[c + 2]);
        v.w = fmaf(v.w, scS[c + 3], shS[c + 3]);
        ((float4*)h)[i] = v;
    }
}

extern "C" void kernel_launch(void* const* d_in, const int* in_sizes, int n_in,
                              void* d_out, int out_size, void* d_ws, size_t ws_size,
                              hipStream_t stream) {
    const float* node_feats = (const float*)d_in[0];
    const float* ef0 = (const float*)d_in[1];
    const float* ef1 = (const float*)d_in[2];
    const int* src = (const int*)d_in[3];
    const int* dst = (const int*)d_in[4];
    const float* We0 = (const float*)d_in[5];
    const float* be0 = (const float*)d_in[6];
    const float* We1 = (const float*)d_in[7];
    const float* be1 = (const float*)d_in[8];
    const float* W1 = (const float*)d_in[9];
    const float* b1 = (const float*)d_in[10];
    const float* W2 = (const float*)d_in[11];
    const float* b2 = (const float*)d_in[12];
    const float* gamma = (const float*)d_in[13];
    const float* beta = (const float*)d_in[14];

    float* out = (float*)d_out;

    // ws layout (65,402,880 B == proven-available footprint)
    float* stats = (float*)d_ws;                          // 65536 B
    float* scaleshift = stats + NSLAB * 2 * EMB;          // 1024 B (layout pad)
    int* counts = (int*)(scaleshift + 256);               // NPAD ints
    int* offsets = counts + NPAD;                         // NPAD ints
    int* cursor = offsets + NPAD;                         // NPAD ints
    int* blockSums = cursor + NPAD;                       // 1024 B
    ushort* w1f = (ushort*)(blockSums + 256);             // 64 KB
    ushort* w2f = w1f + 32768;                            // 64 KB
    int* rec24 = (int*)(w2f + 32768);                     // E*24 B (38.4 MB)
    ushort* nfbf = (ushort*)(rec24 + (size_t)N_EDGES * 6);// N*128 bf16 (25.6 MB)
    size_t needed = (size_t)((char*)(nfbf + (size_t)N_NODES * EMB) - (char*)d_ws);

    if (ws_size >= needed) {
        hipMemsetAsync(d_ws, 0,
            (size_t)(NSLAB * 2 * EMB + 256) * sizeof(float) + (size_t)NPAD * sizeof(int),
            stream);
        setup_kernel<<<2048, 256, 0, stream>>>(
            node_feats, nfbf, dst, counts, W1, W2, w1f, w2f);
        scan_blocksum_kernel<<<NB_SCAN, SCAN_BLK, 0, stream>>>(counts, blockSums);
        scan_final_kernel<<<NB_SCAN, SCAN_BLK, 0, stream>>>(counts, blockSums, offsets, cursor);
        scatter24_kernel<<<(N_EDGES + 255) / 256, 256, 0, stream>>>(
            src, dst, ef0, ef1, cursor, rec24);
        gather4_kernel<<<(N_NODES + 3) / 4, 256, 0, stream>>>(
            nfbf, rec24, offsets, We0, be0, We1, be1, out);
        mlp_mfma_kernel<<<N_NODES / 32, 256, 0, stream>>>(
            out, w1f, w2f, b1, b2, stats);
    } else {
        hipMemsetAsync(stats, 0, (size_t)NSLAB * 2 * EMB * sizeof(float), stream);
        hipMemsetAsync(d_out, 0, (size_t)N_NODES * EMB * sizeof(float), stream);
        edge_scatter_kernel<<<N_EDGES / 2, 256, 0, stream>>>(
            node_feats, ef0, ef1, src, dst, We0, be0, We1, be1, out);
        mlp_kernel<<<N_NODES / BM, 256, 0, stream>>>(out, W1, b1, W2, b2, stats);
    }

    bn_apply_fused_kernel<<<4096, 256, 0, stream>>>(out, stats, gamma, beta);
}